// Round 1
// baseline (715.258 us; speedup 1.0000x reference)
//
#include <hip/hip_runtime.h>

typedef short short8 __attribute__((ext_vector_type(8)));
typedef float f32x4 __attribute__((ext_vector_type(4)));

#define DD 4096      // layer width
#define BM 256       // batch (all rows per block)
#define BN 32        // n-strip per block (128B of W per k-row)
#define KSPLIT 4     // k-split factor
#define KSPAN 1024   // K per block
#define KT 64        // k-tile per iteration
#define NITER 16     // KSPAN / KT
#define WPAD 72      // padded k-extent of LDS W tile (bf16 elems)
#define NLAYER 15

__device__ __forceinline__ unsigned short f2bf(float f) {
  unsigned u = __float_as_uint(f);
  u += 0x7FFFu + ((u >> 16) & 1u);   // round-to-nearest-even
  return (unsigned short)(u >> 16);
}

// fp32 -> bf16 bits for the input activations
__global__ __launch_bounds__(256) void k_tobf16(const float* __restrict__ x,
                                                unsigned short* __restrict__ h) {
  const size_t e = ((size_t)blockIdx.x * 256 + threadIdx.x) * 8;
  f32x4 a = *(const f32x4*)(x + e);
  f32x4 b = *(const f32x4*)(x + e + 4);
  short8 v;
#pragma unroll
  for (int j = 0; j < 4; ++j) { v[j] = (short)f2bf(a[j]); v[4 + j] = (short)f2bf(b[j]); }
  *(short8*)(h + e) = v;
}

// Split-K GEMM: block (n-strip, ks) computes partial [256 x 32] over K range
// [ks*1024, (ks+1)*1024). A (bf16) read direct from global; W (fp32) staged
// to LDS transposed+bf16, double-buffered.
__global__ __launch_bounds__(256) void k_gemm(const unsigned short* __restrict__ A,
                                              const float* __restrict__ W,
                                              float* __restrict__ part) {
  __shared__ __align__(16) unsigned short wlds[2][BN][WPAD];
  const int bid  = blockIdx.x;
  const int ks   = bid & (KSPLIT - 1);   // matches XCD round-robin -> per-XCD A quarter in L2
  const int n0   = (bid >> 2) * BN;
  const int kbeg = ks * KSPAN;
  const int tid  = threadIdx.x;
  const int wave = tid >> 6;
  const int lane = tid & 63;

  // W staging role: thread t loads column n0+sn, k rows [skg*8, skg*8+8)
  const int sn  = tid & 31;
  const int skg = tid >> 5;
  const float* wsrc = W + (size_t)(n0 + sn) + (size_t)skg * 8 * DD;

  const f32x4 fz = {0.f, 0.f, 0.f, 0.f};
  f32x4 acc[4][2];
#pragma unroll
  for (int i = 0; i < 4; ++i)
#pragma unroll
    for (int j = 0; j < 2; ++j) acc[i][j] = fz;

  // prologue: stage tile 0 into buffer 0
  {
    const float* s = wsrc + (size_t)kbeg * DD;
    short8 v;
#pragma unroll
    for (int j = 0; j < 8; ++j) v[j] = (short)f2bf(s[(size_t)j * DD]);
    *(short8*)(&wlds[0][sn][skg * 8]) = v;
  }
  __syncthreads();

  const int mbase = wave * 64;         // 4 waves x 64 rows
  const int rlow  = lane & 15;
  const int kgrp  = (lane >> 4) * 8;

  for (int it = 0; it < NITER; ++it) {
    const int kpos = kbeg + it * KT;
    // prefetch next W tile to registers (hides HBM latency under MFMA)
    float nw[8];
    if (it + 1 < NITER) {
      const float* s = wsrc + (size_t)(kpos + KT) * DD;
#pragma unroll
      for (int j = 0; j < 8; ++j) nw[j] = s[(size_t)j * DD];
    }
    const int buf = it & 1;
#pragma unroll
    for (int kk = 0; kk < 2; ++kk) {
      const int kf = kpos + kk * 32 + kgrp;
      short8 af[4];
#pragma unroll
      for (int mf = 0; mf < 4; ++mf) {
        const int row = mbase + mf * 16 + rlow;
        af[mf] = *(const short8*)(A + (size_t)row * DD + kf);
      }
      short8 bfb[2];
#pragma unroll
      for (int nf = 0; nf < 2; ++nf)
        bfb[nf] = *(const short8*)(&wlds[buf][nf * 16 + rlow][kk * 32 + kgrp]);
#pragma unroll
      for (int mf = 0; mf < 4; ++mf)
#pragma unroll
        for (int nf = 0; nf < 2; ++nf)
          acc[mf][nf] = __builtin_amdgcn_mfma_f32_16x16x32_bf16(af[mf], bfb[nf],
                                                                acc[mf][nf], 0, 0, 0);
    }
    if (it + 1 < NITER) {
      short8 v;
#pragma unroll
      for (int j = 0; j < 8; ++j) v[j] = (short)f2bf(nw[j]);
      *(short8*)(&wlds[buf ^ 1][sn][skg * 8]) = v;
    }
    __syncthreads();
  }

  // write fp32 partial tile (no bias/relu yet)
  float* pdst = part + (size_t)ks * BM * DD;
#pragma unroll
  for (int mf = 0; mf < 4; ++mf) {
    const int rbase = mbase + mf * 16 + (lane >> 4) * 4;
#pragma unroll
    for (int nf = 0; nf < 2; ++nf) {
      const int col = n0 + nf * 16 + (lane & 15);
#pragma unroll
      for (int j = 0; j < 4; ++j)
        pdst[(size_t)(rbase + j) * DD + col] = acc[mf][nf][j];
    }
  }
}

// sum 4 partials + bias, relu, write bf16 h_next (and fp32 d_out on last layer)
__global__ __launch_bounds__(256) void k_epilogue(const float* __restrict__ part,
                                                  const float* __restrict__ bias,
                                                  unsigned short* __restrict__ hout,
                                                  float* __restrict__ fout) {
  const size_t e = ((size_t)blockIdx.x * 256 + threadIdx.x) * 8;
  const int n = (int)(e & (DD - 1));
  const size_t stride = (size_t)BM * DD;
  f32x4 s0 = *(const f32x4*)(part + e);
  f32x4 s1 = *(const f32x4*)(part + e + 4);
#pragma unroll
  for (int q = 1; q < KSPLIT; ++q) {
    s0 += *(const f32x4*)(part + (size_t)q * stride + e);
    s1 += *(const f32x4*)(part + (size_t)q * stride + e + 4);
  }
  s0 += *(const f32x4*)(bias + n);
  s1 += *(const f32x4*)(bias + n + 4);
#pragma unroll
  for (int j = 0; j < 4; ++j) {
    s0[j] = fmaxf(s0[j], 0.f);
    s1[j] = fmaxf(s1[j], 0.f);
  }
  short8 v;
#pragma unroll
  for (int j = 0; j < 4; ++j) { v[j] = (short)f2bf(s0[j]); v[4 + j] = (short)f2bf(s1[j]); }
  *(short8*)(hout + e) = v;
  if (fout) {
    *(f32x4*)(fout + e) = s0;
    *(f32x4*)(fout + e + 4) = s1;
  }
}

extern "C" void kernel_launch(void* const* d_in, const int* in_sizes, int n_in,
                              void* d_out, int out_size, void* d_ws, size_t ws_size,
                              hipStream_t stream) {
  const float* x = (const float*)d_in[0];
  const float* W = (const float*)d_in[1];
  const float* b = (const float*)d_in[2];
  float* out = (float*)d_out;

  char* ws = (char*)d_ws;
  unsigned short* h0 = (unsigned short*)ws;               // 2 MB bf16 activations
  unsigned short* h1 = (unsigned short*)(ws + (1 << 21)); // 2 MB
  float* part = (float*)(ws + (1 << 22));                 // 4 x 4 MB fp32 partials

  k_tobf16<<<512, 256, 0, stream>>>(x, h0);
  unsigned short* hc = h0;
  unsigned short* hn = h1;
  for (int l = 0; l < NLAYER; ++l) {
    k_gemm<<<512, 256, 0, stream>>>(hc, W + (size_t)l * DD * DD, part);
    k_epilogue<<<512, 256, 0, stream>>>(part, b + (size_t)l * DD, hn,
                                        (l == NLAYER - 1) ? out : nullptr);
    unsigned short* t = hc; hc = hn; hn = t;
  }
}